// Round 3
// baseline (114.341 us; speedup 1.0000x reference)
//
#include <hip/hip_runtime.h>

#define SEQ 8192
#define DM  128
#define KS  8            // k-splits
// key tiles: 256 tiles of 32 keys; Kt/Vt stored tiled in MFMA fragment order:
//   chunk p = s*64 + h*32 + q  (16B = 8 bf16)
//   Kt: chunk(p) = K[tile*32+q][16s+8h .. +8)
//   Vt: chunk(p) = V^T[32*(s>>1)+q][tile*32 + 16*(s&1)+8h .. +8)   (s here = w)

typedef __attribute__((ext_vector_type(8)))  short bf16x8;
typedef __attribute__((ext_vector_type(16))) float f32x16;
typedef __attribute__((ext_vector_type(2)))  unsigned int uintx2;

static __device__ __forceinline__ unsigned short f2bf(float f) {
    unsigned int u = __builtin_bit_cast(unsigned int, f);
    u += 0x7FFFu + ((u >> 16) & 1u);
    return (unsigned short)(u >> 16);
}
static __device__ __forceinline__ unsigned int pack2bf(float a, float b) {
    return ((unsigned int)f2bf(b) << 16) | (unsigned int)f2bf(a);
}
static __device__ __forceinline__ float bflo(unsigned int u) {
    return __builtin_bit_cast(float, u << 16);
}
static __device__ __forceinline__ float bfhi(unsigned int u) {
    return __builtin_bit_cast(float, u & 0xFFFF0000u);
}
static __device__ __forceinline__ bf16x8 as_frag(uint4 v) {
    return __builtin_bit_cast(bf16x8, v);
}
// pack truncated bf16 (high halves) via one v_perm -- used only inside softmax p
static __device__ __forceinline__ unsigned int pack2bf_trunc(float a, float b) {
    return __builtin_amdgcn_perm(__builtin_bit_cast(unsigned int, b),
                                 __builtin_bit_cast(unsigned int, a), 0x07060302u);
}
static __device__ __forceinline__ void gl_lds16(const void* g, void* l) {
    __builtin_amdgcn_global_load_lds(
        (const __attribute__((address_space(1))) void*)(unsigned long long)g,
        (__attribute__((address_space(3))) void*)(unsigned int)(unsigned long long)l,
        16, 0, 0);
}
#define CL2 (1.4426950408889634f / 90.50966799187809f)   // log2(e)/sqrt(8192)

// ---- prep: block b handles key-tile b (rows 32b..32b+32) ------------------
__global__ __launch_bounds__(512) void prep_kernel(
        const float* __restrict__ Q, const float* __restrict__ K,
        const float* __restrict__ V,
        uint2* __restrict__ Qb2, uint4* __restrict__ Kt, uint4* __restrict__ Vt) {
    __shared__ float VL[32 * 132 + 4];     // 32 rows x 132 (pad) floats
    const int b = blockIdx.x, tid = threadIdx.x;
    const float4* Q4 = (const float4*)Q;
    const float4* K4 = (const float4*)K;
    const float4* V4 = (const float4*)V;

    // V tile -> LDS (coalesced read, conflict-free b128 writes)
    #pragma unroll
    for (int u = 0; u < 2; ++u) {
        int f4 = u * 512 + tid;
        int k = f4 >> 5, c4 = f4 & 31;
        float4 v = V4[(size_t)b * 1024 + f4];
        *(float4*)(VL + k * 132 + c4 * 4) = v;
    }
    // Q convert (pre-scaled by CL2), row-major bf16
    #pragma unroll
    for (int u = 0; u < 2; ++u) {
        int f4 = u * 512 + tid;
        float4 v = Q4[(size_t)b * 1024 + f4];
        Qb2[(size_t)b * 1024 + f4] = make_uint2(pack2bf(v.x * CL2, v.y * CL2),
                                                pack2bf(v.z * CL2, v.w * CL2));
    }
    // K tiled: chunk p=(s*64+h*32+q) <- K[32b+q][16s+8h..+8)   (512 chunks)
    {
        int p = tid;
        int q = p & 31, h = (p >> 5) & 1, s = p >> 6;
        int fi = (b * 32 + q) * 32 + s * 4 + h * 2;
        float4 a = K4[fi], c = K4[fi + 1];
        Kt[(size_t)b * 512 + p] = make_uint4(pack2bf(a.x, a.y), pack2bf(a.z, a.w),
                                             pack2bf(c.x, c.y), pack2bf(c.z, c.w));
    }
    __syncthreads();
    // V tiled (transposed read from LDS; banks (4k+d)%32 distinct per 32 lanes)
    {
        int p = tid;
        int q = p & 31, h = (p >> 5) & 1, w = p >> 6;
        int d = (w >> 1) * 32 + q;
        int k0 = (w & 1) * 16 + h * 8;
        unsigned int r[4];
        #pragma unroll
        for (int jj = 0; jj < 4; ++jj) {
            float e0 = VL[(k0 + 2 * jj) * 132 + d];
            float e1 = VL[(k0 + 2 * jj + 1) * 132 + d];
            r[jj] = pack2bf(e0, e1);
        }
        Vt[(size_t)b * 512 + p] = make_uint4(r[0], r[1], r[2], r[3]);
    }
}

// ---- main attention -------------------------------------------------------
// Grid 512 = 64 q-tiles x 8 k-splits (2 WG/CU). Block 512 = 4 q-groups x 2 k-halves.
// K staged in LDS (fragment order, conflict-free). V fragments loaded DIRECTLY
// from global (L2/L3-resident, fully coalesced dwordx4) -- halves LDS traffic.
__global__ __launch_bounds__(512, 2) void attn_kernel(
        const unsigned short* __restrict__ Qb,
        const uint4* __restrict__ Kt,
        const uint4* __restrict__ Vt,
        uint2* __restrict__ Opart, float* __restrict__ Lpart) {
    __shared__ __align__(16) char smem[65536];
    __shared__ float Lx[128];
    const int tid = threadIdx.x;
    const int wid = tid >> 6, lane = tid & 63;
    const int i = wid & 3, j = wid >> 2;
    const int q = lane & 31, h = lane >> 5;
    const int qt = blockIdx.x & 63, ks = blockIdx.x >> 6;
    const int qbase = qt * 128 + i * 32;
    const int tile0 = ks * 32 + j * 16;      // 16 tiles per k-half

    // persistent Q fragment (pre-scaled): Q[qbase+q][16s+8h+jj]
    uint4 qf[8];
    {
        const unsigned short* qrow = Qb + (qbase + q) * DM + 8 * h;
        #pragma unroll
        for (int s = 0; s < 8; ++s) qf[s] = *(const uint4*)(qrow + 16 * s);
    }

    f32x16 oacc[4];
    #pragma unroll
    for (int mb = 0; mb < 4; ++mb)
        #pragma unroll
        for (int r = 0; r < 16; ++r) oacc[mb][r] = 0.f;
    float ls0 = 0.f, ls1 = 0.f, ls2 = 0.f, ls3 = 0.f;

    // K-only staging: per j-half, 2 buffers x 8 KB
    char* const mybuf = smem + j * 16384;
    auto stage = [&](int buf, int tile) {
        char* base = mybuf + buf * 8192;
        const uint4* kt = Kt + (size_t)tile * 512;
        #pragma unroll
        for (int u = 0; u < 2; ++u) {
            int ki = i * 2 + u;
            gl_lds16(kt + ki * 64 + lane, base + ki * 1024);
        }
    };

    stage(0, tile0);
    #pragma unroll 1
    for (int t = 0; t < 16; ++t) {
        __syncthreads();
        // V fragments straight from global (coalesced, L2-resident); issued
        // first so they're oldest in vmcnt order -> PV's wait leaves the
        // stage loads in flight.
        uint4 vf[8];
        {
            const uint4* vt = Vt + (size_t)(tile0 + t) * 512 + lane;
            #pragma unroll
            for (int w = 0; w < 8; ++w) vf[w] = vt[w * 64];
        }
        if (t < 15) stage((t + 1) & 1, tile0 + t + 1);
        const char* kl = mybuf + (t & 1) * 8192 + lane * 16;

        uint4 kf[8];
        #pragma unroll
        for (int s = 0; s < 8; ++s) kf[s] = *(const uint4*)(kl + s * 1024);

        f32x16 sacc;
        #pragma unroll
        for (int r = 0; r < 16; ++r) sacc[r] = 0.f;
        __builtin_amdgcn_s_setprio(1);
        #pragma unroll
        for (int s = 0; s < 8; ++s)
            sacc = __builtin_amdgcn_mfma_f32_32x32x16_bf16(
                       as_frag(kf[s]), as_frag(qf[s]), sacc, 0, 0, 0);
        __builtin_amdgcn_s_setprio(0);

        float p[16];
        #pragma unroll
        for (int r = 0; r < 16; ++r) p[r] = __builtin_amdgcn_exp2f(sacc[r]);
        #pragma unroll
        for (int r = 0; r < 4; ++r) {
            ls0 += p[4 * r + 0]; ls1 += p[4 * r + 1];
            ls2 += p[4 * r + 2]; ls3 += p[4 * r + 3];
        }
        unsigned int pk[8];
        #pragma unroll
        for (int jj = 0; jj < 8; ++jj) pk[jj] = pack2bf_trunc(p[2 * jj], p[2 * jj + 1]);
        // lane-half exchange via permlane32_swap (VALU) instead of ds_bpermute.
        // HW semantics (disambiguated by R2 failure): swap(A,B) ->
        //   ret0 = {l<32: A(l),    l>=32: B(l-32)}
        //   ret1 = {l<32: A(l+32), l>=32: B(l)}
        // needed: B0.x = {h0: pk0, h1: pk2(l-32)}, B0.z = {h0: pk0(l+32), h1: pk2}
        uint4 B0, B1;
        {
            uintx2 r0 = __builtin_amdgcn_permlane32_swap(pk[0], pk[2], false, false);
            uintx2 r1 = __builtin_amdgcn_permlane32_swap(pk[1], pk[3], false, false);
            uintx2 r4 = __builtin_amdgcn_permlane32_swap(pk[4], pk[6], false, false);
            uintx2 r5 = __builtin_amdgcn_permlane32_swap(pk[5], pk[7], false, false);
            B0.x = r0[0];  B0.z = r0[1];
            B0.y = r1[0];  B0.w = r1[1];
            B1.x = r4[0];  B1.z = r4[1];
            B1.y = r5[0];  B1.w = r5[1];
        }

        __builtin_amdgcn_s_setprio(1);
        #pragma unroll
        for (int mb = 0; mb < 4; ++mb) {
            oacc[mb] = __builtin_amdgcn_mfma_f32_32x32x16_bf16(
                           as_frag(vf[mb * 2 + 0]), as_frag(B0), oacc[mb], 0, 0, 0);
            oacc[mb] = __builtin_amdgcn_mfma_f32_32x32x16_bf16(
                           as_frag(vf[mb * 2 + 1]), as_frag(B1), oacc[mb], 0, 0, 0);
        }
        __builtin_amdgcn_s_setprio(0);
    }
    float lsum = (ls0 + ls1) + (ls2 + ls3);

    // ---- epilogue: combine k-halves, store bf16 partial in [d][q] layout --
    float l2 = lsum + __shfl_xor(lsum, 32);
    __syncthreads();
    float* Lg = (float*)(smem + i * 16384);   // [128 d][32 q] per q-group
    if (j == 0) {
        #pragma unroll
        for (int mb = 0; mb < 4; ++mb)
            #pragma unroll
            for (int r = 0; r < 16; ++r) {
                int dl = 32 * mb + (r & 3) + 8 * (r >> 2) + 4 * h;
                Lg[dl * 32 + q] = oacc[mb][r];     // bank=q: 2-way, free
            }
        if (h == 0) Lx[i * 32 + q] = l2;
    }
    __syncthreads();
    if (j == 1) {
        #pragma unroll
        for (int mb = 0; mb < 4; ++mb)
            #pragma unroll
            for (int r = 0; r < 16; ++r) {
                int dl = 32 * mb + (r & 3) + 8 * (r >> 2) + 4 * h;
                Lg[dl * 32 + q] += oacc[mb][r];
            }
        if (h == 0) Lpart[(size_t)ks * SEQ + qbase + q] = Lx[i * 32 + q] + l2;
    }
    __syncthreads();
    // Opart tile (ks,qt): [128 d][128 q] bf16, coalesced 16B-equivalent stores
    #pragma unroll
    for (int u = 0; u < 8; ++u) {
        int idx = u * 512 + tid;
        int rd = idx >> 5, c4 = idx & 31;
        int ig = c4 >> 3, q4 = c4 & 7;
        float4 v = *(const float4*)(smem + ig * 16384 + (rd * 8 + q4) * 16);
        Opart[(((size_t)(ks * 64 + qt)) * 128 + rd) * 32 + c4] =
            make_uint2(pack2bf(v.x, v.y), pack2bf(v.z, v.w));
    }
}

// ---- reduce: sum 8 splits, transpose [d][q]->[q][d], normalize ------------
__global__ __launch_bounds__(512) void reduce_kernel(
        const uint2* __restrict__ Opart, const float* __restrict__ Lpart,
        float* __restrict__ Out) {
    __shared__ float T[32 * 132 + 4];       // [32 d][132 pad] fp32
    __shared__ float Rinv[128];
    const int tid = threadIdx.x;
    const int qt = blockIdx.x & 63, dq = blockIdx.x >> 6;
    if (tid < 128) {
        float L = 0.f;
        #pragma unroll
        for (int ks = 0; ks < KS; ++ks) L += Lpart[(size_t)ks * SEQ + qt * 128 + tid];
        Rinv[tid] = 1.0f / L;
    }
    const int c = tid & 31, dsub = tid >> 5;     // dsub 0..15
    float4 acc[2];
    #pragma unroll
    for (int rr = 0; rr < 2; ++rr) { acc[rr].x = acc[rr].y = acc[rr].z = acc[rr].w = 0.f; }
    #pragma unroll
    for (int ks = 0; ks < KS; ++ks) {
        #pragma unroll
        for (int rr = 0; rr < 2; ++rr) {
            int d_l = rr * 16 + dsub;
            uint2 w = Opart[(((size_t)(ks * 64 + qt)) * 128 + dq * 32 + d_l) * 32 + c];
            acc[rr].x += bflo(w.x); acc[rr].y += bfhi(w.x);
            acc[rr].z += bflo(w.y); acc[rr].w += bfhi(w.y);
        }
    }
    #pragma unroll
    for (int rr = 0; rr < 2; ++rr)
        *(float4*)(T + (rr * 16 + dsub) * 132 + c * 4) = acc[rr];
    __syncthreads();
    const int q_l = tid >> 2, part = tid & 3;
    float r = Rinv[q_l];
    #pragma unroll
    for (int g = 0; g < 2; ++g) {
        int d0 = part * 8 + g * 4;
        float4 o;
        o.x = T[(d0 + 0) * 132 + q_l] * r;
        o.y = T[(d0 + 1) * 132 + q_l] * r;
        o.z = T[(d0 + 2) * 132 + q_l] * r;
        o.w = T[(d0 + 3) * 132 + q_l] * r;
        *(float4*)(Out + ((size_t)(qt * 128 + q_l)) * DM + dq * 32 + d0) = o;
    }
}

extern "C" void kernel_launch(void* const* d_in, const int* in_sizes, int n_in,
                              void* d_out, int out_size, void* d_ws, size_t ws_size,
                              hipStream_t stream) {
    const float* Q = (const float*)d_in[0];
    const float* K = (const float*)d_in[1];
    const float* V = (const float*)d_in[2];
    char* ws = (char*)d_ws;
    uint2* Qb2  = (uint2*)ws;                                   // 2 MiB
    uint4* Kt   = (uint4*)(ws + 2 * 1024 * 1024);               // 2 MiB
    uint4* Vt   = (uint4*)(ws + 4 * 1024 * 1024);               // 2 MiB
    float* Lpart= (float*)(ws + 6 * 1024 * 1024);               // 256 KiB
    uint2* Opart= (uint2*)(ws + 6 * 1024 * 1024 + 262144);      // 16 MiB bf16
    float* Out  = (float*)d_out;

    prep_kernel<<<256, 512, 0, stream>>>(Q, K, V, Qb2, Kt, Vt);
    attn_kernel<<<512, 512, 0, stream>>>((const unsigned short*)Qb2, Kt, Vt,
                                         Opart, Lpart);
    reduce_kernel<<<256, 512, 0, stream>>>(Opart, Lpart, Out);
}

// Round 4
// 112.208 us; speedup vs baseline: 1.0190x; 1.0190x over previous
//
#include <hip/hip_runtime.h>

#define SEQ 8192
#define DM  128
#define KS  8            // k-splits
// key tiles: 256 tiles of 32 keys; Kt/Vt stored tiled in MFMA fragment order:
//   chunk p = s*64 + h*32 + q  (16B = 8 bf16)
//   Kt: chunk(p) = K[tile*32+q][16s+8h .. +8)
//   Vt: chunk(p) = V^T[32*(s>>1)+q][tile*32 + 16*(s&1)+8h .. +8)   (s here = w)

typedef __attribute__((ext_vector_type(8)))  short bf16x8;
typedef __attribute__((ext_vector_type(16))) float f32x16;
typedef __attribute__((ext_vector_type(2)))  unsigned int uintx2;

static __device__ __forceinline__ unsigned short f2bf(float f) {
    unsigned int u = __builtin_bit_cast(unsigned int, f);
    u += 0x7FFFu + ((u >> 16) & 1u);
    return (unsigned short)(u >> 16);
}
static __device__ __forceinline__ unsigned int pack2bf(float a, float b) {
    return ((unsigned int)f2bf(b) << 16) | (unsigned int)f2bf(a);
}
static __device__ __forceinline__ float bflo(unsigned int u) {
    return __builtin_bit_cast(float, u << 16);
}
static __device__ __forceinline__ float bfhi(unsigned int u) {
    return __builtin_bit_cast(float, u & 0xFFFF0000u);
}
static __device__ __forceinline__ bf16x8 as_frag(uint4 v) {
    return __builtin_bit_cast(bf16x8, v);
}
// pack truncated bf16 (high halves) via one v_perm -- used only inside softmax p
static __device__ __forceinline__ unsigned int pack2bf_trunc(float a, float b) {
    return __builtin_amdgcn_perm(__builtin_bit_cast(unsigned int, b),
                                 __builtin_bit_cast(unsigned int, a), 0x07060302u);
}
static __device__ __forceinline__ void gl_lds16(const void* g, void* l) {
    __builtin_amdgcn_global_load_lds(
        (const __attribute__((address_space(1))) void*)(unsigned long long)g,
        (__attribute__((address_space(3))) void*)(unsigned int)(unsigned long long)l,
        16, 0, 0);
}
#define CL2 (1.4426950408889634f / 90.50966799187809f)   // log2(e)/sqrt(8192)

// ---- prep: block b handles key-tile b (rows 32b..32b+32) ------------------
__global__ __launch_bounds__(512) void prep_kernel(
        const float* __restrict__ Q, const float* __restrict__ K,
        const float* __restrict__ V,
        uint2* __restrict__ Qb2, uint4* __restrict__ Kt, uint4* __restrict__ Vt) {
    __shared__ float VL[32 * 132 + 4];     // 32 rows x 132 (pad) floats
    const int b = blockIdx.x, tid = threadIdx.x;
    const float4* Q4 = (const float4*)Q;
    const float4* K4 = (const float4*)K;
    const float4* V4 = (const float4*)V;

    // V tile -> LDS (coalesced read, conflict-free b128 writes)
    #pragma unroll
    for (int u = 0; u < 2; ++u) {
        int f4 = u * 512 + tid;
        int k = f4 >> 5, c4 = f4 & 31;
        float4 v = V4[(size_t)b * 1024 + f4];
        *(float4*)(VL + k * 132 + c4 * 4) = v;
    }
    // Q convert (pre-scaled by CL2), row-major bf16
    #pragma unroll
    for (int u = 0; u < 2; ++u) {
        int f4 = u * 512 + tid;
        float4 v = Q4[(size_t)b * 1024 + f4];
        Qb2[(size_t)b * 1024 + f4] = make_uint2(pack2bf(v.x * CL2, v.y * CL2),
                                                pack2bf(v.z * CL2, v.w * CL2));
    }
    // K tiled: chunk p=(s*64+h*32+q) <- K[32b+q][16s+8h..+8)   (512 chunks)
    {
        int p = tid;
        int q = p & 31, h = (p >> 5) & 1, s = p >> 6;
        int fi = (b * 32 + q) * 32 + s * 4 + h * 2;
        float4 a = K4[fi], c = K4[fi + 1];
        Kt[(size_t)b * 512 + p] = make_uint4(pack2bf(a.x, a.y), pack2bf(a.z, a.w),
                                             pack2bf(c.x, c.y), pack2bf(c.z, c.w));
    }
    __syncthreads();
    // V tiled (transposed read from LDS; banks (4k+d)%32 distinct per 32 lanes)
    {
        int p = tid;
        int q = p & 31, h = (p >> 5) & 1, w = p >> 6;
        int d = (w >> 1) * 32 + q;
        int k0 = (w & 1) * 16 + h * 8;
        unsigned int r[4];
        #pragma unroll
        for (int jj = 0; jj < 4; ++jj) {
            float e0 = VL[(k0 + 2 * jj) * 132 + d];
            float e1 = VL[(k0 + 2 * jj + 1) * 132 + d];
            r[jj] = pack2bf(e0, e1);
        }
        Vt[(size_t)b * 512 + p] = make_uint4(r[0], r[1], r[2], r[3]);
    }
}

// ---- main attention -------------------------------------------------------
// Grid 512 = 64 q-tiles x 8 k-splits (2 WG/CU). Block 512 = 4 q-groups x 2 k-halves.
// K+V staged in LDS via global_load_lds double-buffer (fragment order, zero
// bank conflicts). Softmax lane-half exchange via permlane32_swap (VALU pipe).
__global__ __launch_bounds__(512, 2) void attn_kernel(
        const unsigned short* __restrict__ Qb,
        const uint4* __restrict__ Kt,
        const uint4* __restrict__ Vt,
        uint2* __restrict__ Opart, float* __restrict__ Lpart) {
    __shared__ __align__(16) char smem[65536];
    __shared__ float Lx[128];
    const int tid = threadIdx.x;
    const int wid = tid >> 6, lane = tid & 63;
    const int i = wid & 3, j = wid >> 2;
    const int q = lane & 31, h = lane >> 5;
    const int qt = blockIdx.x & 63, ks = blockIdx.x >> 6;
    const int qbase = qt * 128 + i * 32;
    const int tile0 = ks * 32 + j * 16;      // 16 tiles per k-half

    // persistent Q fragment (pre-scaled): Q[qbase+q][16s+8h+jj]
    uint4 qf[8];
    {
        const unsigned short* qrow = Qb + (qbase + q) * DM + 8 * h;
        #pragma unroll
        for (int s = 0; s < 8; ++s) qf[s] = *(const uint4*)(qrow + 16 * s);
    }

    f32x16 oacc[4];
    #pragma unroll
    for (int mb = 0; mb < 4; ++mb)
        #pragma unroll
        for (int r = 0; r < 16; ++r) oacc[mb][r] = 0.f;
    float ls0 = 0.f, ls1 = 0.f, ls2 = 0.f, ls3 = 0.f;

    char* const mybuf = smem + j * 32768;    // [2 bufs][K 8K | Vt 8K]
    auto stage = [&](int buf, int tile) {
        char* base = mybuf + buf * 16384;
        const uint4* kt = Kt + (size_t)tile * 512;
        const uint4* vt = Vt + (size_t)tile * 512;
        #pragma unroll
        for (int u = 0; u < 2; ++u) {
            int ki = i * 2 + u;
            gl_lds16(kt + ki * 64 + lane, base + ki * 1024);
            gl_lds16(vt + ki * 64 + lane, base + 8192 + ki * 1024);
        }
    };

    stage(0, tile0);
    #pragma unroll 1
    for (int t = 0; t < 16; ++t) {
        __syncthreads();
        if (t < 15) stage((t + 1) & 1, tile0 + t + 1);
        const char* kl = mybuf + (t & 1) * 16384 + lane * 16;

        uint4 kf[8];
        #pragma unroll
        for (int s = 0; s < 8; ++s) kf[s] = *(const uint4*)(kl + s * 1024);

        // QK^T: two independent 4-deep MFMA chains (halves dep-latency chain)
        f32x16 sa, sb;
        #pragma unroll
        for (int r = 0; r < 16; ++r) { sa[r] = 0.f; sb[r] = 0.f; }
        __builtin_amdgcn_s_setprio(1);
        #pragma unroll
        for (int s = 0; s < 4; ++s) {
            sa = __builtin_amdgcn_mfma_f32_32x32x16_bf16(
                     as_frag(kf[s]), as_frag(qf[s]), sa, 0, 0, 0);
            sb = __builtin_amdgcn_mfma_f32_32x32x16_bf16(
                     as_frag(kf[s + 4]), as_frag(qf[s + 4]), sb, 0, 0, 0);
        }
        __builtin_amdgcn_s_setprio(0);

        uint4 vf[8];
        #pragma unroll
        for (int w = 0; w < 8; ++w) vf[w] = *(const uint4*)(kl + 8192 + w * 1024);

        float p[16];
        #pragma unroll
        for (int r = 0; r < 16; ++r) p[r] = __builtin_amdgcn_exp2f(sa[r] + sb[r]);
        #pragma unroll
        for (int r = 0; r < 4; ++r) {
            ls0 += p[4 * r + 0]; ls1 += p[4 * r + 1];
            ls2 += p[4 * r + 2]; ls3 += p[4 * r + 3];
        }
        unsigned int pk[8];
        #pragma unroll
        for (int jj = 0; jj < 8; ++jj) pk[jj] = pack2bf_trunc(p[2 * jj], p[2 * jj + 1]);
        // lane-half exchange via permlane32_swap (VALU; semantics HW-verified R3):
        //   swap(A,B) -> ret0 = {l<32: A(l),    l>=32: B(l-32)}
        //               ret1 = {l<32: A(l+32), l>=32: B(l)}
        uint4 B0, B1;
        {
            uintx2 r0 = __builtin_amdgcn_permlane32_swap(pk[0], pk[2], false, false);
            uintx2 r1 = __builtin_amdgcn_permlane32_swap(pk[1], pk[3], false, false);
            uintx2 r4 = __builtin_amdgcn_permlane32_swap(pk[4], pk[6], false, false);
            uintx2 r5 = __builtin_amdgcn_permlane32_swap(pk[5], pk[7], false, false);
            B0.x = r0[0];  B0.z = r0[1];
            B0.y = r1[0];  B0.w = r1[1];
            B1.x = r4[0];  B1.z = r4[1];
            B1.y = r5[0];  B1.w = r5[1];
        }

        __builtin_amdgcn_s_setprio(1);
        #pragma unroll
        for (int mb = 0; mb < 4; ++mb) {
            oacc[mb] = __builtin_amdgcn_mfma_f32_32x32x16_bf16(
                           as_frag(vf[mb * 2 + 0]), as_frag(B0), oacc[mb], 0, 0, 0);
            oacc[mb] = __builtin_amdgcn_mfma_f32_32x32x16_bf16(
                           as_frag(vf[mb * 2 + 1]), as_frag(B1), oacc[mb], 0, 0, 0);
        }
        __builtin_amdgcn_s_setprio(0);
    }
    float lsum = (ls0 + ls1) + (ls2 + ls3);

    // ---- epilogue: combine k-halves, store bf16 partial in [d][q] layout --
    float l2 = lsum + __shfl_xor(lsum, 32);
    __syncthreads();
    float* Lg = (float*)(smem + i * 16384);   // [128 d][32 q] per q-group
    if (j == 0) {
        #pragma unroll
        for (int mb = 0; mb < 4; ++mb)
            #pragma unroll
            for (int r = 0; r < 16; ++r) {
                int dl = 32 * mb + (r & 3) + 8 * (r >> 2) + 4 * h;
                Lg[dl * 32 + q] = oacc[mb][r];     // bank=q: 2-way, free
            }
        if (h == 0) Lx[i * 32 + q] = l2;
    }
    __syncthreads();
    if (j == 1) {
        #pragma unroll
        for (int mb = 0; mb < 4; ++mb)
            #pragma unroll
            for (int r = 0; r < 16; ++r) {
                int dl = 32 * mb + (r & 3) + 8 * (r >> 2) + 4 * h;
                Lg[dl * 32 + q] += oacc[mb][r];
            }
        if (h == 0) Lpart[(size_t)ks * SEQ + qbase + q] = Lx[i * 32 + q] + l2;
    }
    __syncthreads();
    // Opart tile (ks,qt): [128 d][128 q] bf16, coalesced 16B-equivalent stores
    #pragma unroll
    for (int u = 0; u < 8; ++u) {
        int idx = u * 512 + tid;
        int rd = idx >> 5, c4 = idx & 31;
        int ig = c4 >> 3, q4 = c4 & 7;
        float4 v = *(const float4*)(smem + ig * 16384 + (rd * 8 + q4) * 16);
        Opart[(((size_t)(ks * 64 + qt)) * 128 + rd) * 32 + c4] =
            make_uint2(pack2bf(v.x, v.y), pack2bf(v.z, v.w));
    }
}

// ---- reduce: sum 8 splits, transpose [d][q]->[q][d], normalize ------------
__global__ __launch_bounds__(512) void reduce_kernel(
        const uint2* __restrict__ Opart, const float* __restrict__ Lpart,
        float* __restrict__ Out) {
    __shared__ float T[32 * 132 + 4];       // [32 d][132 pad] fp32
    __shared__ float Rinv[128];
    const int tid = threadIdx.x;
    const int qt = blockIdx.x & 63, dq = blockIdx.x >> 6;
    if (tid < 128) {
        float L = 0.f;
        #pragma unroll
        for (int ks = 0; ks < KS; ++ks) L += Lpart[(size_t)ks * SEQ + qt * 128 + tid];
        Rinv[tid] = 1.0f / L;
    }
    const int c = tid & 31, dsub = tid >> 5;     // dsub 0..15
    float4 acc[2];
    #pragma unroll
    for (int rr = 0; rr < 2; ++rr) { acc[rr].x = acc[rr].y = acc[rr].z = acc[rr].w = 0.f; }
    #pragma unroll
    for (int ks = 0; ks < KS; ++ks) {
        #pragma unroll
        for (int rr = 0; rr < 2; ++rr) {
            int d_l = rr * 16 + dsub;
            uint2 w = Opart[(((size_t)(ks * 64 + qt)) * 128 + dq * 32 + d_l) * 32 + c];
            acc[rr].x += bflo(w.x); acc[rr].y += bfhi(w.x);
            acc[rr].z += bflo(w.y); acc[rr].w += bfhi(w.y);
        }
    }
    #pragma unroll
    for (int rr = 0; rr < 2; ++rr)
        *(float4*)(T + (rr * 16 + dsub) * 132 + c * 4) = acc[rr];
    __syncthreads();
    const int q_l = tid >> 2, part = tid & 3;
    float r = Rinv[q_l];
    #pragma unroll
    for (int g = 0; g < 2; ++g) {
        int d0 = part * 8 + g * 4;
        float4 o;
        o.x = T[(d0 + 0) * 132 + q_l] * r;
        o.y = T[(d0 + 1) * 132 + q_l] * r;
        o.z = T[(d0 + 2) * 132 + q_l] * r;
        o.w = T[(d0 + 3) * 132 + q_l] * r;
        *(float4*)(Out + ((size_t)(qt * 128 + q_l)) * DM + dq * 32 + d0) = o;
    }
}

extern "C" void kernel_launch(void* const* d_in, const int* in_sizes, int n_in,
                              void* d_out, int out_size, void* d_ws, size_t ws_size,
                              hipStream_t stream) {
    const float* Q = (const float*)d_in[0];
    const float* K = (const float*)d_in[1];
    const float* V = (const float*)d_in[2];
    char* ws = (char*)d_ws;
    uint2* Qb2  = (uint2*)ws;                                   // 2 MiB
    uint4* Kt   = (uint4*)(ws + 2 * 1024 * 1024);               // 2 MiB
    uint4* Vt   = (uint4*)(ws + 4 * 1024 * 1024);               // 2 MiB
    float* Lpart= (float*)(ws + 6 * 1024 * 1024);               // 256 KiB
    uint2* Opart= (uint2*)(ws + 6 * 1024 * 1024 + 262144);      // 16 MiB bf16
    float* Out  = (float*)d_out;

    prep_kernel<<<256, 512, 0, stream>>>(Q, K, V, Qb2, Kt, Vt);
    attn_kernel<<<512, 512, 0, stream>>>((const unsigned short*)Qb2, Kt, Vt,
                                         Opart, Lpart);
    reduce_kernel<<<256, 512, 0, stream>>>(Opart, Lpart, Out);
}